// Round 5
// baseline (122.091 us; speedup 1.0000x reference)
//
#include <hip/hip_runtime.h>

// Problem constants (match reference)
#define BB 64
#define PP 8400
#define TT 100
#define TG 4             // targets per block
#define NGRP (TT / TG)   // 25 groups per batch -> grid = 64*25 = 1600
#define NBLK (BB * NGRP)
// 1 - 2^-20: conservative filter margin. Skip exact div only when the
// rounded quotient is PROVABLY < bar (3 rounding ulps << 2^-20).
#define ONE_MEPS 0.99999904632568359375f

// One fused kernel: per-(batch, 4-target-group) argmax with div-skipping
// filter, masked squared error, global sum via last-block reduction.
__global__ __launch_bounds__(256) void yolo_match_kernel(
    const float* __restrict__ pred,     // [B, P, 5]
    const float* __restrict__ tgt,      // [B, T, 5]
    const int*   __restrict__ lengths,  // [B]
    float*       __restrict__ partials, // [NBLK]
    unsigned*    __restrict__ count,    // zeroed by memsetAsync each launch
    float*       __restrict__ out)      // [1]
{
#pragma clang fp contract(off)
    // XCD-aware decode: block i -> XCD (i % 8); all 25 groups of batch b
    // land on one XCD so the 168 KB pred panel stays L2-resident.
    const int blkraw = blockIdx.x;
    const int x    = blkraw & 7;
    const int r    = blkraw >> 3;          // 0..199
    const int bhi  = r / NGRP;             // 0..7
    const int grp  = r - bhi * NGRP;       // 0..24
    const int b    = x + 8 * bhi;          // 0..63
    const int t0   = grp * TG;
    const int tid  = threadIdx.x;
    const int lane = tid & 63;
    const int wid  = tid >> 6;             // 0..3

    const float*  pb  = pred + (size_t)b * PP * 5;
    const float4* pb4 = (const float4*)pb;
    const float*  tb  = tgt + ((size_t)b * TT + t0) * 5;

    // Per-target corners + area in registers.
    float tx1[TG], ty1[TG], tx2[TG], ty2[TG], ta[TG];
#pragma unroll
    for (int g = 0; g < TG; ++g) {
        const float tcx = tb[g * 5 + 1], tcy = tb[g * 5 + 2];
        const float tw  = tb[g * 5 + 3], th  = tb[g * 5 + 4];
        tx1[g] = tcx - tw * 0.5f;
        ty1[g] = tcy - th * 0.5f;
        tx2[g] = tcx + tw * 0.5f;
        ty2[g] = tcy + th * 0.5f;
        ta[g]  = (tx2[g] - tx1[g]) * (ty2[g] - ty1[g]);
    }

    float best[TG];   // exact RN(inter/denom) of current winner
    int   bidx[TG];
    float barf[TG];   // (lower bound of known max) * (1-2^-20); filter bar
#pragma unroll
    for (int g = 0; g < TG; ++g) { best[g] = -1.0f; bidx[g] = 0; barf[g] = -1.0f; }

    __shared__ float s_red[4][TG];

    // Main loop: 4 boxes per thread-iteration via 5 aligned float4 loads.
    // iter 0 covers boxes 0..1023; afterwards the block shares its max as a
    // filter bar for boxes >= 1024 (all higher-index => skip-on-tie safe).
    int iter = 0;
    for (int g0 = tid; g0 < PP / 4; g0 += 256, ++iter) {
        const float4 v0 = pb4[g0 * 5 + 0];
        const float4 v1 = pb4[g0 * 5 + 1];
        const float4 v2 = pb4[g0 * 5 + 2];
        const float4 v3 = pb4[g0 * 5 + 3];
        const float4 v4 = pb4[g0 * 5 + 4];
        const float cxs[4] = { v0.y, v1.z, v2.w, v4.x };
        const float cys[4] = { v0.z, v1.w, v3.x, v4.y };
        const float wss[4] = { v0.w, v2.x, v3.y, v4.z };
        const float hss[4] = { v1.x, v2.y, v3.z, v4.w };

#pragma unroll
        for (int j = 0; j < 4; ++j) {
            const float px1 = cxs[j] - wss[j] * 0.5f;
            const float py1 = cys[j] - hss[j] * 0.5f;
            const float px2 = cxs[j] + wss[j] * 0.5f;
            const float py2 = cys[j] + hss[j] * 0.5f;
            const float area_p = (px2 - px1) * (py2 - py1);
            const int   p = g0 * 4 + j;

#pragma unroll
            for (int g = 0; g < TG; ++g) {
                const float ix1 = fmaxf(px1, tx1[g]);
                const float iy1 = fmaxf(py1, ty1[g]);
                const float ix2 = fminf(px2, tx2[g]);
                const float iy2 = fminf(py2, ty2[g]);
                const float inter = fmaxf(ix2 - ix1, 0.0f) * fmaxf(iy2 - iy1, 0.0f);
                // numpy eval order: ((area_p + area_t) - inter) + 1e-6
                const float denom = ((area_p + ta[g]) - inter) + 1e-6f;
                // Conservative filter: if inter <= barf*denom then the exact
                // quotient is < bar (or a higher-index tie) -> cannot win.
                if (__builtin_expect(inter > barf[g] * denom, 0)) {
                    const float q = inter / denom;   // IEEE div — bit-match numpy
                    if (q > best[g]) { best[g] = q; bidx[g] = p; }
                    barf[g] = fmaxf(barf[g], q * ONE_MEPS);
                }
            }
        }

        if (iter == 0) {
            // Share block-wide VALUE max (from boxes 0..1023) as the bar.
#pragma unroll
            for (int g = 0; g < TG; ++g) {
                float bv = best[g];
                for (int off = 32; off > 0; off >>= 1)
                    bv = fmaxf(bv, __shfl_down(bv, off, 64));
                if (lane == 0) s_red[wid][g] = bv;
            }
            __syncthreads();
#pragma unroll
            for (int g = 0; g < TG; ++g) {
                const float gb = fmaxf(fmaxf(s_red[0][g], s_red[1][g]),
                                       fmaxf(s_red[2][g], s_red[3][g]));
                barf[g] = fmaxf(barf[g], gb * ONE_MEPS);
            }
        }
    }

    // Final argmax reduce: wave shuffle, then cross-wave via LDS.
    __shared__ float s_best[4][TG];
    __shared__ int   s_bidx[4][TG];
    __shared__ float s_sq[TG];

#pragma unroll
    for (int g = 0; g < TG; ++g) {
        float bv = best[g];
        int   bi = bidx[g];
        for (int off = 32; off > 0; off >>= 1) {
            const float ob = __shfl_down(bv, off, 64);
            const int   oi = __shfl_down(bi, off, 64);
            if (ob > bv || (ob == bv && oi < bi)) { bv = ob; bi = oi; }
        }
        if (lane == 0) { s_best[wid][g] = bv; s_bidx[wid][g] = bi; }
    }
    __syncthreads();

    if (tid < TG) {
        const int g = tid;
        float bv = s_best[0][g];
        int   bi = s_bidx[0][g];
#pragma unroll
        for (int w = 1; w < 4; ++w) {
            const float ob = s_best[w][g];
            const int   oi = s_bidx[w][g];
            if (ob > bv || (ob == bv && oi < bi)) { bv = ob; bi = oi; }
        }
        const float* mp = pb + bi * 5;
        const float* tp = tb + g * 5;
        float sq = 0.0f;
        for (int k = 0; k < 5; ++k) {
            const float d = mp[k] - tp[k];
            sq += d * d;
        }
        const bool valid = ((t0 + g) < lengths[b]);
        s_sq[g] = valid ? sq : 0.0f;
    }
    __syncthreads();

    // Last-block global reduction (deterministic final sum order).
    __shared__ bool amLast;
    if (tid == 0) {
        partials[blkraw] = s_sq[0] + s_sq[1] + s_sq[2] + s_sq[3];
        __threadfence();                       // release partial store
        const unsigned old = atomicAdd(count, 1u);
        amLast = (old == (unsigned)(NBLK - 1));
    }
    __syncthreads();

    if (amLast) {
        __threadfence();                       // acquire all partials
        float s = 0.0f;
        for (int i = tid; i < NBLK; i += 256) s += partials[i];
        __shared__ float sm[256];
        sm[tid] = s;
        __syncthreads();
        for (int off = 128; off > 0; off >>= 1) {
            if (tid < off) sm[tid] += sm[tid + off];
            __syncthreads();
        }
        if (tid == 0) out[0] = sm[0] / (float)BB;
    }
}

extern "C" void kernel_launch(void* const* d_in, const int* in_sizes, int n_in,
                              void* d_out, int out_size, void* d_ws, size_t ws_size,
                              hipStream_t stream) {
    const float* pred    = (const float*)d_in[0]; // [B,P,5] f32
    const float* tgt     = (const float*)d_in[1]; // [B,T,5] f32
    const int*   lengths = (const int*)d_in[2];   // [B]
    float* out = (float*)d_out;

    unsigned* count    = (unsigned*)d_ws;             // 4 bytes
    float*    partials = ((float*)d_ws) + 1;          // NBLK floats

    hipMemsetAsync(count, 0, sizeof(unsigned), stream);
    yolo_match_kernel<<<NBLK, 256, 0, stream>>>(pred, tgt, lengths,
                                                partials, count, out);
}

// Round 6
// 118.579 us; speedup vs baseline: 1.0296x; 1.0296x over previous
//
#include <hip/hip_runtime.h>

// Problem constants (match reference)
#define BB 64
#define PP 8400
#define TT 100
#define TG 5             // targets per block
#define NGRP (TT / TG)   // 20 groups per batch -> grid = 64*20 = 1280 = 5 blocks/CU
#define NBLK (BB * NGRP)

// One fused kernel: per-(batch, 5-target-group) argmax (branchless, exact
// IEEE div to bit-match numpy), masked squared error, global sum via
// last-block reduction. XCD swizzle keeps each batch's 168 KB pred panel on
// one XCD's L2.
__global__ __launch_bounds__(256, 4) void yolo_match_kernel(
    const float* __restrict__ pred,     // [B, P, 5]
    const float* __restrict__ tgt,      // [B, T, 5]
    const int*   __restrict__ lengths,  // [B]
    float*       __restrict__ partials, // [NBLK]
    unsigned*    __restrict__ count,    // zeroed by memsetAsync each launch
    float*       __restrict__ out)      // [1]
{
#pragma clang fp contract(off)
    // XCD-aware decode: block i -> XCD (i % 8); all 20 groups of batch b
    // land on one XCD. 1280/8 = 160 blocks/XCD = 8 panels = 1.34 MB << 4 MB L2.
    const int blkraw = blockIdx.x;
    const int x    = blkraw & 7;
    const int r    = blkraw >> 3;          // 0..159
    const int bhi  = r / NGRP;             // 0..7
    const int grp  = r - bhi * NGRP;       // 0..19
    const int b    = x + 8 * bhi;          // 0..63
    const int t0   = grp * TG;
    const int tid  = threadIdx.x;
    const int lane = tid & 63;
    const int wid  = tid >> 6;             // 0..3

    const float*  pb  = pred + (size_t)b * PP * 5;
    const float4* pb4 = (const float4*)pb;
    const float*  tb  = tgt + ((size_t)b * TT + t0) * 5;

    // Per-target corners + area in registers.
    float tx1[TG], ty1[TG], tx2[TG], ty2[TG], ta[TG];
#pragma unroll
    for (int g = 0; g < TG; ++g) {
        const float tcx = tb[g * 5 + 1], tcy = tb[g * 5 + 2];
        const float tw  = tb[g * 5 + 3], th  = tb[g * 5 + 4];
        tx1[g] = tcx - tw * 0.5f;
        ty1[g] = tcy - th * 0.5f;
        tx2[g] = tcx + tw * 0.5f;
        ty2[g] = tcy + th * 0.5f;
        ta[g]  = (tx2[g] - tx1[g]) * (ty2[g] - ty1[g]);
    }

    float best[TG];
    int   bidx[TG];
#pragma unroll
    for (int g = 0; g < TG; ++g) { best[g] = -1.0f; bidx[g] = 0; }

    // 4 boxes per step via 5 aligned float4 loads; unroll 2 steps so the
    // scheduler can overlap the next step's loads with this step's math.
#pragma unroll 2
    for (int g0 = tid; g0 < PP / 4; g0 += 256) {
        const float4 v0 = pb4[g0 * 5 + 0];
        const float4 v1 = pb4[g0 * 5 + 1];
        const float4 v2 = pb4[g0 * 5 + 2];
        const float4 v3 = pb4[g0 * 5 + 3];
        const float4 v4 = pb4[g0 * 5 + 4];
        // box j fields (conf,cx,cy,w,h) at float offset 5j within the 20:
        const float cxs[4] = { v0.y, v1.z, v2.w, v4.x };
        const float cys[4] = { v0.z, v1.w, v3.x, v4.y };
        const float wss[4] = { v0.w, v2.x, v3.y, v4.z };
        const float hss[4] = { v1.x, v2.y, v3.z, v4.w };

#pragma unroll
        for (int j = 0; j < 4; ++j) {
            const float px1 = cxs[j] - wss[j] * 0.5f;
            const float py1 = cys[j] - hss[j] * 0.5f;
            const float px2 = cxs[j] + wss[j] * 0.5f;
            const float py2 = cys[j] + hss[j] * 0.5f;
            const float area_p = (px2 - px1) * (py2 - py1);
            const int   p = g0 * 4 + j;

#pragma unroll
            for (int g = 0; g < TG; ++g) {
                const float ix1 = fmaxf(px1, tx1[g]);
                const float iy1 = fmaxf(py1, ty1[g]);
                const float ix2 = fminf(px2, tx2[g]);
                const float iy2 = fminf(py2, ty2[g]);
                const float inter = fmaxf(ix2 - ix1, 0.0f) * fmaxf(iy2 - iy1, 0.0f);
                // numpy eval order: ((area_p + area_t) - inter) + 1e-6
                const float denom = ((area_p + ta[g]) - inter) + 1e-6f;
                const float iou   = inter / denom;   // IEEE div — bit-match numpy
                if (iou > best[g]) { best[g] = iou; bidx[g] = p; }  // -> cndmask
            }
        }
    }

    // Final argmax reduce: wave shuffle, then cross-wave via LDS.
    __shared__ float s_best[4][TG];
    __shared__ int   s_bidx[4][TG];
    __shared__ float s_sq[TG];

#pragma unroll
    for (int g = 0; g < TG; ++g) {
        float bv = best[g];
        int   bi = bidx[g];
        for (int off = 32; off > 0; off >>= 1) {
            const float ob = __shfl_down(bv, off, 64);
            const int   oi = __shfl_down(bi, off, 64);
            if (ob > bv || (ob == bv && oi < bi)) { bv = ob; bi = oi; }
        }
        if (lane == 0) { s_best[wid][g] = bv; s_bidx[wid][g] = bi; }
    }
    __syncthreads();

    if (tid < TG) {
        const int g = tid;
        float bv = s_best[0][g];
        int   bi = s_bidx[0][g];
#pragma unroll
        for (int w = 1; w < 4; ++w) {
            const float ob = s_best[w][g];
            const int   oi = s_bidx[w][g];
            if (ob > bv || (ob == bv && oi < bi)) { bv = ob; bi = oi; }
        }
        const float* mp = pb + bi * 5;
        const float* tp = tb + g * 5;
        float sq = 0.0f;
        for (int k = 0; k < 5; ++k) {
            const float d = mp[k] - tp[k];
            sq += d * d;
        }
        const bool valid = ((t0 + g) < lengths[b]);
        s_sq[g] = valid ? sq : 0.0f;
    }
    __syncthreads();

    // Last-block global reduction (deterministic final sum order).
    __shared__ bool amLast;
    if (tid == 0) {
        partials[blkraw] = ((s_sq[0] + s_sq[1]) + (s_sq[2] + s_sq[3])) + s_sq[4];
        __threadfence();                       // release partial store
        const unsigned old = atomicAdd(count, 1u);
        amLast = (old == (unsigned)(NBLK - 1));
    }
    __syncthreads();

    if (amLast) {
        __threadfence();                       // acquire all partials
        float s = 0.0f;
        for (int i = tid; i < NBLK; i += 256) s += partials[i];
        __shared__ float sm[256];
        sm[tid] = s;
        __syncthreads();
        for (int off = 128; off > 0; off >>= 1) {
            if (tid < off) sm[tid] += sm[tid + off];
            __syncthreads();
        }
        if (tid == 0) out[0] = sm[0] / (float)BB;
    }
}

extern "C" void kernel_launch(void* const* d_in, const int* in_sizes, int n_in,
                              void* d_out, int out_size, void* d_ws, size_t ws_size,
                              hipStream_t stream) {
    const float* pred    = (const float*)d_in[0]; // [B,P,5] f32
    const float* tgt     = (const float*)d_in[1]; // [B,T,5] f32
    const int*   lengths = (const int*)d_in[2];   // [B]
    float* out = (float*)d_out;

    unsigned* count    = (unsigned*)d_ws;             // 4 bytes
    float*    partials = ((float*)d_ws) + 1;          // NBLK floats

    hipMemsetAsync(count, 0, sizeof(unsigned), stream);
    yolo_match_kernel<<<NBLK, 256, 0, stream>>>(pred, tgt, lengths,
                                                partials, count, out);
}

// Round 7
// 105.457 us; speedup vs baseline: 1.1577x; 1.1244x over previous
//
#include <hip/hip_runtime.h>

// Problem constants (match reference)
#define BB 64
#define PP 8400
#define TT 100
#define TG 5             // targets per block
#define NGRP (TT / TG)   // 20 groups per batch -> grid = 64*20 = 1280 = 5 blocks/CU
#define NBLK (BB * NGRP)

// Kernel 1: one block per (batch, 5-target-group). Each thread processes 8
// consecutive pred boxes per iteration via 10 aligned float4 loads -> 40
// independent IoU+div chains for ILP (latency-bound fix; round-4 was 36 VGPR
// and serialized on div chains). Branchless exact IEEE div (bit-match numpy).
// XCD swizzle keeps each batch's 168 KB pred panel on one XCD's L2.
// NO device-scope atomics/fences: they flush per-XCD L2 (round-6 regression).
__global__ __launch_bounds__(256) void yolo_match_kernel(
    const float* __restrict__ pred,    // [B, P, 5]
    const float* __restrict__ tgt,     // [B, T, 5]
    const int*   __restrict__ lengths, // [B]
    float* __restrict__ ws)            // [NBLK] block partial sums
{
#pragma clang fp contract(off)
    // XCD-aware decode: block i -> XCD (i % 8); all 20 groups of batch b
    // land on one XCD. 1280/8 = 160 blocks/XCD = 8 panels = 1.34 MB << 4 MB L2.
    const int blkraw = blockIdx.x;
    const int x    = blkraw & 7;
    const int r    = blkraw >> 3;          // 0..159
    const int bhi  = r / NGRP;             // 0..7
    const int grp  = r - bhi * NGRP;       // 0..19
    const int b    = x + 8 * bhi;          // 0..63
    const int t0   = grp * TG;
    const int tid  = threadIdx.x;
    const int lane = tid & 63;
    const int wid  = tid >> 6;             // 0..3

    const float*  pb  = pred + (size_t)b * PP * 5;
    const float4* pb4 = (const float4*)pb;
    const float*  tb  = tgt + ((size_t)b * TT + t0) * 5;

    // Per-target corners + area in registers.
    float tx1[TG], ty1[TG], tx2[TG], ty2[TG], ta[TG];
#pragma unroll
    for (int g = 0; g < TG; ++g) {
        const float tcx = tb[g * 5 + 1], tcy = tb[g * 5 + 2];
        const float tw  = tb[g * 5 + 3], th  = tb[g * 5 + 4];
        tx1[g] = tcx - tw * 0.5f;
        ty1[g] = tcy - th * 0.5f;
        tx2[g] = tcx + tw * 0.5f;
        ty2[g] = tcy + th * 0.5f;
        ta[g]  = (tx2[g] - tx1[g]) * (ty2[g] - ty1[g]);
    }

    float best[TG];
    int   bidx[TG];
#pragma unroll
    for (int g = 0; g < TG; ++g) { best[g] = -1.0f; bidx[g] = 0; }

    // 8 boxes per step via 10 aligned float4 loads (40 floats).
    // Field map: box j, field f at float 5j+f; quad = (5j+f)>>2, comp = &3.
    for (int g0 = tid; g0 < PP / 8; g0 += 256) {
        float4 q[10];
#pragma unroll
        for (int k = 0; k < 10; ++k) q[k] = pb4[g0 * 10 + k];

        float cxs[8], cys[8], wss[8], hss[8];
#pragma unroll
        for (int h = 0; h < 2; ++h) {      // two 4-box halves, same pattern
            const float4 v0 = q[5 * h + 0];
            const float4 v1 = q[5 * h + 1];
            const float4 v2 = q[5 * h + 2];
            const float4 v3 = q[5 * h + 3];
            const float4 v4 = q[5 * h + 4];
            cxs[4 * h + 0] = v0.y; cys[4 * h + 0] = v0.z; wss[4 * h + 0] = v0.w; hss[4 * h + 0] = v1.x;
            cxs[4 * h + 1] = v1.z; cys[4 * h + 1] = v1.w; wss[4 * h + 1] = v2.x; hss[4 * h + 1] = v2.y;
            cxs[4 * h + 2] = v2.w; cys[4 * h + 2] = v3.x; wss[4 * h + 2] = v3.y; hss[4 * h + 2] = v3.z;
            cxs[4 * h + 3] = v4.x; cys[4 * h + 3] = v4.y; wss[4 * h + 3] = v4.z; hss[4 * h + 3] = v4.w;
        }

#pragma unroll
        for (int j = 0; j < 8; ++j) {
            const float px1 = cxs[j] - wss[j] * 0.5f;
            const float py1 = cys[j] - hss[j] * 0.5f;
            const float px2 = cxs[j] + wss[j] * 0.5f;
            const float py2 = cys[j] + hss[j] * 0.5f;
            const float area_p = (px2 - px1) * (py2 - py1);
            const int   p = g0 * 8 + j;

#pragma unroll
            for (int g = 0; g < TG; ++g) {
                const float ix1 = fmaxf(px1, tx1[g]);
                const float iy1 = fmaxf(py1, ty1[g]);
                const float ix2 = fminf(px2, tx2[g]);
                const float iy2 = fminf(py2, ty2[g]);
                const float inter = fmaxf(ix2 - ix1, 0.0f) * fmaxf(iy2 - iy1, 0.0f);
                // numpy eval order: ((area_p + area_t) - inter) + 1e-6
                const float denom = ((area_p + ta[g]) - inter) + 1e-6f;
                const float iou   = inter / denom;   // IEEE div — bit-match numpy
                if (iou > best[g]) { best[g] = iou; bidx[g] = p; }  // -> cndmask
            }
        }
    }

    // Final argmax reduce: wave shuffle, then cross-wave via LDS.
    __shared__ float s_best[4][TG];
    __shared__ int   s_bidx[4][TG];
    __shared__ float s_sq[TG];

#pragma unroll
    for (int g = 0; g < TG; ++g) {
        float bv = best[g];
        int   bi = bidx[g];
        for (int off = 32; off > 0; off >>= 1) {
            const float ob = __shfl_down(bv, off, 64);
            const int   oi = __shfl_down(bi, off, 64);
            if (ob > bv || (ob == bv && oi < bi)) { bv = ob; bi = oi; }
        }
        if (lane == 0) { s_best[wid][g] = bv; s_bidx[wid][g] = bi; }
    }
    __syncthreads();

    if (tid < TG) {
        const int g = tid;
        float bv = s_best[0][g];
        int   bi = s_bidx[0][g];
#pragma unroll
        for (int w = 1; w < 4; ++w) {
            const float ob = s_best[w][g];
            const int   oi = s_bidx[w][g];
            if (ob > bv || (ob == bv && oi < bi)) { bv = ob; bi = oi; }
        }
        const float* mp = pb + bi * 5;
        const float* tp = tb + g * 5;
        float sq = 0.0f;
        for (int k = 0; k < 5; ++k) {
            const float d = mp[k] - tp[k];
            sq += d * d;
        }
        const bool valid = ((t0 + g) < lengths[b]);
        s_sq[g] = valid ? sq : 0.0f;
    }
    __syncthreads();

    if (tid == 0) {
        ws[blkraw] = ((s_sq[0] + s_sq[1]) + (s_sq[2] + s_sq[3])) + s_sq[4];
    }
}

// Kernel 2: sum ws[0 .. NBLK) -> out[0] = sum / B
__global__ __launch_bounds__(256) void yolo_reduce_kernel(
    const float* __restrict__ ws,
    float* __restrict__ out)
{
    const int tid = threadIdx.x;
    float s = 0.0f;
    for (int i = tid; i < NBLK; i += 256) s += ws[i];

    __shared__ float sm[256];
    sm[tid] = s;
    __syncthreads();
    for (int off = 128; off > 0; off >>= 1) {
        if (tid < off) sm[tid] += sm[tid + off];
        __syncthreads();
    }
    if (tid == 0) out[0] = sm[0] / (float)BB;
}

extern "C" void kernel_launch(void* const* d_in, const int* in_sizes, int n_in,
                              void* d_out, int out_size, void* d_ws, size_t ws_size,
                              hipStream_t stream) {
    const float* pred    = (const float*)d_in[0]; // [B,P,5] f32
    const float* tgt     = (const float*)d_in[1]; // [B,T,5] f32
    const int*   lengths = (const int*)d_in[2];   // [B]
    float* out = (float*)d_out;
    float* ws  = (float*)d_ws;                    // NBLK floats = 5.12 KB

    yolo_match_kernel<<<NBLK, 256, 0, stream>>>(pred, tgt, lengths, ws);
    yolo_reduce_kernel<<<1, 256, 0, stream>>>(ws, out);
}